// Round 3
// baseline (1327.395 us; speedup 1.0000x reference)
//
#include <hip/hip_runtime.h>

#define F 128
#define H 64
#define O 16

#define BSHIFT 7
#define BSZ 128   // nodes per dst-bucket

// ---------- CSR build ----------
__global__ void k_zero(int* __restrict__ p, int n) {
    int i = blockIdx.x * blockDim.x + threadIdx.x;
    if (i < n) p[i] = 0;
}

__global__ void k_degree(const int* __restrict__ dstv, int* __restrict__ deg, int E) {
    int i = blockIdx.x * blockDim.x + threadIdx.x;
    if (i < E) atomicAdd(&deg[dstv[i]], 1);
}

__global__ void k_dis(const int* __restrict__ deg, float* __restrict__ dis, int N) {
    int i = blockIdx.x * blockDim.x + threadIdx.x;
    if (i < N) dis[i] = rsqrtf((float)deg[i] + 1.0f);
}

// block-level exclusive scan of deg -> local (stored in row_ptr), block sums -> partials
__global__ void k_scan1(const int* __restrict__ deg, int* __restrict__ local,
                        int* __restrict__ partials, int N) {
    __shared__ int s[256];
    int tid = threadIdx.x;
    int i = blockIdx.x * 256 + tid;
    int v = (i < N) ? deg[i] : 0;
    s[tid] = v;
    __syncthreads();
    for (int off = 1; off < 256; off <<= 1) {
        int t = (tid >= off) ? s[tid - off] : 0;
        __syncthreads();
        s[tid] += t;
        __syncthreads();
    }
    if (i < N) local[i] = s[tid] - v;  // exclusive within block
    if (tid == 255) partials[blockIdx.x] = s[255];
}

__global__ void k_scan2(int* __restrict__ partials, int NB) {
    __shared__ int s[1024];
    int tid = threadIdx.x;
    int v = (tid < NB) ? partials[tid] : 0;
    s[tid] = v;
    __syncthreads();
    for (int off = 1; off < 1024; off <<= 1) {
        int t = (tid >= off) ? s[tid - off] : 0;
        __syncthreads();
        s[tid] += t;
        __syncthreads();
    }
    partials[tid] = s[tid] - v;  // exclusive
}

__global__ void k_scan3(int* __restrict__ row_ptr, const int* __restrict__ partials,
                        int N, int E) {
    int i = blockIdx.x * blockDim.x + threadIdx.x;
    if (i < N) {
        row_ptr[i] += partials[i >> 8];
    } else if (i == N) {
        row_ptr[N] = E;
    }
}

// bucket cursors: start of each 128-node bucket in CSR order
__global__ void k_bcur(const int* __restrict__ row_ptr, int* __restrict__ bcur, int NBK) {
    int i = blockIdx.x * blockDim.x + threadIdx.x;
    if (i < NBK) bcur[i] = row_ptr[i << BSHIFT];
}

// Phase A: scatter packed (src<<7 | local_dst) into dst-bucket regions.
// Writes within a bucket go to an ascending frontier -> good line utilization.
__global__ void k_bucketA(const int* __restrict__ src, const int* __restrict__ dstv,
                          int* __restrict__ bcur, int* __restrict__ bdata, int E) {
    int i = blockIdx.x * blockDim.x + threadIdx.x;
    if (i < E) {
        int s = src[i];
        int d = dstv[i];
        int b = d >> BSHIFT;
        int pos = atomicAdd(&bcur[b], 1);
        bdata[pos] = (s << BSHIFT) | (d & (BSZ - 1));
    }
}

// Phase B: one block per bucket; LDS cursors place each edge at its exact CSR slot.
// All global stores confined to the bucket's ~16KB window (L2-resident).
__global__ __launch_bounds__(256) void k_csrB(const int* __restrict__ bdata,
                                              const int* __restrict__ row_ptr,
                                              int* __restrict__ col, int N) {
    __shared__ int cur[BSZ];
    int b = blockIdx.x;
    int node0 = b << BSHIFT;
    int nloc = min(BSZ, N - node0);
    for (int t = threadIdx.x; t < nloc; t += 256) cur[t] = row_ptr[node0 + t];
    __syncthreads();
    int start = row_ptr[node0];
    int end = row_ptr[node0 + nloc];
    for (int p = start + threadIdx.x; p < end; p += 256) {
        int v = bdata[p];
        int pos = atomicAdd(&cur[v & (BSZ - 1)], 1);
        col[pos] = v >> BSHIFT;
    }
}

// ---------- layer 1: h1p = (x @ W1) * dis[row] ----------
__global__ __launch_bounds__(256) void k_gemm1(const float* __restrict__ x,
                                               const float* __restrict__ W1,
                                               const float* __restrict__ dis,
                                               float* __restrict__ h1p, int N) {
    __shared__ float w[F * H];  // 32 KB
    for (int t = threadIdx.x; t < F * H; t += 256) w[t] = W1[t];
    __syncthreads();
    int wave = threadIdx.x >> 6, lane = threadIdx.x & 63;
    for (int r = blockIdx.x * 4 + wave; r < N; r += gridDim.x * 4) {
        const float* xr = x + (size_t)r * F;
        float acc = 0.f;
#pragma unroll
        for (int k = 0; k < F; k++) acc = fmaf(xr[k], w[k * H + lane], acc);
        h1p[(size_t)r * H + lane] = acc * dis[r];
    }
}

// ---------- layer 1 aggregation: 1 wave/node, 4 edges in flight ----------
__global__ __launch_bounds__(256) void k_gather1(const float* __restrict__ h1p,
                                                 const float* __restrict__ dis,
                                                 const int* __restrict__ row_ptr,
                                                 const int* __restrict__ col,
                                                 const float* __restrict__ b1,
                                                 float* __restrict__ z, int N) {
    int node = blockIdx.x * 4 + (threadIdx.x >> 6);
    if (node >= N) return;
    int lane = threadIdx.x & 63;
    int g = lane >> 4;    // edge group 0..3
    int t = lane & 15;    // feature quad
    float4 acc = {0.f, 0.f, 0.f, 0.f};
    int e = row_ptr[node + 1];
#pragma unroll 4
    for (int p = row_ptr[node] + g; p < e; p += 4) {
        int s = col[p];
        float4 v = *(const float4*)(h1p + (size_t)s * H + t * 4);
        acc.x += v.x; acc.y += v.y; acc.z += v.z; acc.w += v.w;
    }
#pragma unroll
    for (int off = 16; off < 64; off <<= 1) {
        acc.x += __shfl_xor(acc.x, off);
        acc.y += __shfl_xor(acc.y, off);
        acc.z += __shfl_xor(acc.z, off);
        acc.w += __shfl_xor(acc.w, off);
    }
    if (g == 0) {
        float dn = dis[node];
        float4 self = *(const float4*)(h1p + (size_t)node * H + t * 4);
        float4 bb = *(const float4*)(b1 + t * 4);
        float4 o;
        o.x = fmaxf(fmaf(acc.x + self.x, dn, bb.x), 0.f);
        o.y = fmaxf(fmaf(acc.y + self.y, dn, bb.y), 0.f);
        o.z = fmaxf(fmaf(acc.z + self.z, dn, bb.z), 0.f);
        o.w = fmaxf(fmaf(acc.w + self.w, dn, bb.w), 0.f);
        *(float4*)(z + (size_t)node * H + t * 4) = o;
    }
}

// ---------- layer 2: h2p = (z @ W2) * dis[row] ----------
__global__ __launch_bounds__(256) void k_gemm2(const float* __restrict__ z,
                                               const float* __restrict__ W2,
                                               const float* __restrict__ dis,
                                               float* __restrict__ h2p, int N) {
    __shared__ float w[H * O];  // 4 KB
    for (int t = threadIdx.x; t < H * O; t += 256) w[t] = W2[t];
    __syncthreads();
    int idx = blockIdx.x * 256 + threadIdx.x;
    int row = idx >> 4, j = idx & 15;
    if (row >= N) return;
    const float* zr = z + (size_t)row * H;
    float acc = 0.f;
#pragma unroll
    for (int k = 0; k < H; k++) acc = fmaf(zr[k], w[k * O + j], acc);
    h2p[idx] = acc * dis[row];
}

// ---------- layer 2 aggregation: 1 wave/node, 16 edges in flight ----------
__global__ __launch_bounds__(256) void k_gather2(const float* __restrict__ h2p,
                                                 const float* __restrict__ dis,
                                                 const int* __restrict__ row_ptr,
                                                 const int* __restrict__ col,
                                                 const float* __restrict__ b2,
                                                 float* __restrict__ z2, int N) {
    int node = blockIdx.x * 4 + (threadIdx.x >> 6);
    if (node >= N) return;
    int lane = threadIdx.x & 63;
    int g = lane >> 2;    // edge group 0..15
    int t = lane & 3;     // feature quad
    float4 acc = {0.f, 0.f, 0.f, 0.f};
    int e = row_ptr[node + 1];
    for (int p = row_ptr[node] + g; p < e; p += 16) {
        int s = col[p];
        float4 v = *(const float4*)(h2p + (size_t)s * O + t * 4);
        acc.x += v.x; acc.y += v.y; acc.z += v.z; acc.w += v.w;
    }
#pragma unroll
    for (int off = 4; off < 64; off <<= 1) {
        acc.x += __shfl_xor(acc.x, off);
        acc.y += __shfl_xor(acc.y, off);
        acc.z += __shfl_xor(acc.z, off);
        acc.w += __shfl_xor(acc.w, off);
    }
    if (g == 0) {
        float dn = dis[node];
        float4 self = *(const float4*)(h2p + (size_t)node * O + t * 4);
        float4 bb = *(const float4*)(b2 + t * 4);
        float4 o;
        o.x = fmaf(acc.x + self.x, dn, bb.x);
        o.y = fmaf(acc.y + self.y, dn, bb.y);
        o.z = fmaf(acc.z + self.z, dn, bb.z);
        o.w = fmaf(acc.w + self.w, dn, bb.w);
        *(float4*)(z2 + (size_t)node * O + t * 4) = o;
    }
}

// ---------- link prediction logits: 4 lanes per pair ----------
__global__ __launch_bounds__(256) void k_logits(const float* __restrict__ z2,
                                                const int* __restrict__ pos,
                                                const int* __restrict__ neg,
                                                float* __restrict__ out, int P, int Q) {
    int tid = blockIdx.x * 256 + threadIdx.x;
    int i = tid >> 2;
    if (i >= P + Q) return;
    int k = tid & 3;
    int a, b;
    if (i < P) { a = pos[i]; b = pos[P + i]; }
    else       { int t = i - P; a = neg[t]; b = neg[Q + t]; }
    float4 va = *(const float4*)(z2 + (size_t)a * O + k * 4);
    float4 vb = *(const float4*)(z2 + (size_t)b * O + k * 4);
    float r = va.x * vb.x + va.y * vb.y + va.z * vb.z + va.w * vb.w;
    r += __shfl_xor(r, 1);
    r += __shfl_xor(r, 2);
    if (k == 0) out[i] = r;
}

extern "C" void kernel_launch(void* const* d_in, const int* in_sizes, int n_in,
                              void* d_out, int out_size, void* d_ws, size_t ws_size,
                              hipStream_t stream) {
    const float* x   = (const float*)d_in[0];
    const int*   ei  = (const int*)d_in[1];
    const int*   pos = (const int*)d_in[2];
    const int*   neg = (const int*)d_in[3];
    const float* W1  = (const float*)d_in[4];
    const float* b1  = (const float*)d_in[5];
    const float* W2  = (const float*)d_in[6];
    const float* b2  = (const float*)d_in[7];
    float* out = (float*)d_out;

    int N = in_sizes[0] / F;
    int E = in_sizes[1] / 2;
    int P = in_sizes[2] / 2;
    int Q = in_sizes[3] / 2;
    const int* src  = ei;
    const int* dstv = ei + E;

    int NB  = (N + 255) / 256;       // scan blocks, <= 1024
    int Npad = NB * 256;
    int Epad = (E + 63) & ~63;
    int NBK = (N + BSZ - 1) / BSZ;   // dst buckets
    int NBKpad = (NBK + 255) & ~255;

    // workspace layout (all offsets 256B-aligned)
    int*   deg      = (int*)d_ws;
    float* dis      = (float*)(deg + Npad);
    int*   row_ptr  = (int*)(dis + Npad);        // N+1 entries (Npad+256 reserved)
    int*   bcur     = row_ptr + Npad + 256;      // NBK entries
    int*   partials = bcur + NBKpad;             // 1024 entries
    int*   col      = partials + 1024;           // E entries
    float* h1p      = (float*)(col + Epad);      // N*H floats
    float* z        = h1p + (size_t)N * H;       // N*H
    float* h2p      = z + (size_t)N * H;         // N*O
    float* z2       = h2p + (size_t)N * O;       // N*O
    int*   bdata    = (int*)h1p;                 // E ints, aliases h1p (dead until k_gemm1)

    // CSR build
    k_zero<<<(Npad + 255) / 256, 256, 0, stream>>>(deg, Npad);
    k_degree<<<(E + 255) / 256, 256, 0, stream>>>(dstv, deg, E);
    k_dis<<<(N + 255) / 256, 256, 0, stream>>>(deg, dis, N);
    k_scan1<<<NB, 256, 0, stream>>>(deg, row_ptr, partials, N);
    k_scan2<<<1, 1024, 0, stream>>>(partials, NB);
    k_scan3<<<(N + 256) / 256, 256, 0, stream>>>(row_ptr, partials, N, E);
    k_bcur<<<(NBK + 255) / 256, 256, 0, stream>>>(row_ptr, bcur, NBK);
    k_bucketA<<<(E + 255) / 256, 256, 0, stream>>>(src, dstv, bcur, bdata, E);
    k_csrB<<<NBK, 256, 0, stream>>>(bdata, row_ptr, col, N);

    // layer 1
    k_gemm1<<<1024, 256, 0, stream>>>(x, W1, dis, h1p, N);
    k_gather1<<<(N + 3) / 4, 256, 0, stream>>>(h1p, dis, row_ptr, col, b1, z, N);

    // layer 2
    k_gemm2<<<(N * O + 255) / 256, 256, 0, stream>>>(z, W2, dis, h2p, N);
    k_gather2<<<(N + 3) / 4, 256, 0, stream>>>(h2p, dis, row_ptr, col, b2, z2, N);

    // logits
    k_logits<<<((P + Q) * 4 + 255) / 256, 256, 0, stream>>>(z2, pos, neg, out, P, Q);
}

// Round 4
// 614.897 us; speedup vs baseline: 2.1587x; 2.1587x over previous
//
#include <hip/hip_runtime.h>

#define F 128
#define H 64
#define O 16

// ---------- CSR build (rank-based, single atomic pass) ----------
__global__ void k_zero(int* __restrict__ p, int n) {
    int i = blockIdx.x * blockDim.x + threadIdx.x;
    if (i < n) p[i] = 0;
}

// fused degree + rank: one atomic per edge, rank written coalesced
__global__ void k_rank(const int* __restrict__ dstv, int* __restrict__ cnt,
                       int* __restrict__ rank, int E) {
    int i = blockIdx.x * blockDim.x + threadIdx.x;
    if (i < E) rank[i] = atomicAdd(&cnt[dstv[i]], 1);
}

__global__ void k_dis(const int* __restrict__ deg, float* __restrict__ dis, int N) {
    int i = blockIdx.x * blockDim.x + threadIdx.x;
    if (i < N) dis[i] = rsqrtf((float)deg[i] + 1.0f);
}

// block-level exclusive scan of deg -> local (stored in row_ptr), block sums -> partials
__global__ void k_scan1(const int* __restrict__ deg, int* __restrict__ local,
                        int* __restrict__ partials, int N) {
    __shared__ int s[256];
    int tid = threadIdx.x;
    int i = blockIdx.x * 256 + tid;
    int v = (i < N) ? deg[i] : 0;
    s[tid] = v;
    __syncthreads();
    for (int off = 1; off < 256; off <<= 1) {
        int t = (tid >= off) ? s[tid - off] : 0;
        __syncthreads();
        s[tid] += t;
        __syncthreads();
    }
    if (i < N) local[i] = s[tid] - v;  // exclusive within block
    if (tid == 255) partials[blockIdx.x] = s[255];
}

__global__ void k_scan2(int* __restrict__ partials, int NB) {
    __shared__ int s[1024];
    int tid = threadIdx.x;
    int v = (tid < NB) ? partials[tid] : 0;
    s[tid] = v;
    __syncthreads();
    for (int off = 1; off < 1024; off <<= 1) {
        int t = (tid >= off) ? s[tid - off] : 0;
        __syncthreads();
        s[tid] += t;
        __syncthreads();
    }
    partials[tid] = s[tid] - v;  // exclusive
}

__global__ void k_scan3(int* __restrict__ row_ptr, const int* __restrict__ partials,
                        int N, int E) {
    int i = blockIdx.x * blockDim.x + threadIdx.x;
    if (i < N) {
        row_ptr[i] += partials[i >> 8];
    } else if (i == N) {
        row_ptr[N] = E;
    }
}

// atomic-free placement: pos is exact, store is the only random access
__global__ void k_place(const int* __restrict__ src, const int* __restrict__ dstv,
                        const int* __restrict__ rank, const int* __restrict__ row_ptr,
                        int* __restrict__ col, int E) {
    int i = blockIdx.x * blockDim.x + threadIdx.x;
    if (i < E) {
        col[row_ptr[dstv[i]] + rank[i]] = src[i];
    }
}

// ---------- layer 1: h1p = (x @ W1) * dis[row] ----------
__global__ __launch_bounds__(256) void k_gemm1(const float* __restrict__ x,
                                               const float* __restrict__ W1,
                                               const float* __restrict__ dis,
                                               float* __restrict__ h1p, int N) {
    __shared__ float w[F * H];  // 32 KB
    for (int t = threadIdx.x; t < F * H; t += 256) w[t] = W1[t];
    __syncthreads();
    int wave = threadIdx.x >> 6, lane = threadIdx.x & 63;
    for (int r = blockIdx.x * 4 + wave; r < N; r += gridDim.x * 4) {
        const float* xr = x + (size_t)r * F;
        float acc = 0.f;
#pragma unroll
        for (int k = 0; k < F; k++) acc = fmaf(xr[k], w[k * H + lane], acc);
        h1p[(size_t)r * H + lane] = acc * dis[r];
    }
}

// ---------- layer 1 aggregation: 1 wave/node, 4 edges in flight ----------
// z[i] = relu( dis[i]*( sum_{s in N(i)} h1p[s] + h1p[i] ) + b1 )
__global__ __launch_bounds__(256) void k_gather1(const float* __restrict__ h1p,
                                                 const float* __restrict__ dis,
                                                 const int* __restrict__ row_ptr,
                                                 const int* __restrict__ col,
                                                 const float* __restrict__ b1,
                                                 float* __restrict__ z, int N) {
    int node = blockIdx.x * 4 + (threadIdx.x >> 6);
    if (node >= N) return;
    int lane = threadIdx.x & 63;
    int g = lane >> 4;    // edge group 0..3
    int t = lane & 15;    // feature quad
    float4 acc = {0.f, 0.f, 0.f, 0.f};
    int e = row_ptr[node + 1];
#pragma unroll 8
    for (int p = row_ptr[node] + g; p < e; p += 4) {
        int s = col[p];
        float4 v = *(const float4*)(h1p + (size_t)s * H + t * 4);
        acc.x += v.x; acc.y += v.y; acc.z += v.z; acc.w += v.w;
    }
#pragma unroll
    for (int off = 16; off < 64; off <<= 1) {
        acc.x += __shfl_xor(acc.x, off);
        acc.y += __shfl_xor(acc.y, off);
        acc.z += __shfl_xor(acc.z, off);
        acc.w += __shfl_xor(acc.w, off);
    }
    if (g == 0) {
        float dn = dis[node];
        float4 self = *(const float4*)(h1p + (size_t)node * H + t * 4);
        float4 bb = *(const float4*)(b1 + t * 4);
        float4 o;
        o.x = fmaxf(fmaf(acc.x + self.x, dn, bb.x), 0.f);
        o.y = fmaxf(fmaf(acc.y + self.y, dn, bb.y), 0.f);
        o.z = fmaxf(fmaf(acc.z + self.z, dn, bb.z), 0.f);
        o.w = fmaxf(fmaf(acc.w + self.w, dn, bb.w), 0.f);
        *(float4*)(z + (size_t)node * H + t * 4) = o;
    }
}

// ---------- layer 2: h2p = (z @ W2) * dis[row] ----------
__global__ __launch_bounds__(256) void k_gemm2(const float* __restrict__ z,
                                               const float* __restrict__ W2,
                                               const float* __restrict__ dis,
                                               float* __restrict__ h2p, int N) {
    __shared__ float w[H * O];  // 4 KB
    for (int t = threadIdx.x; t < H * O; t += 256) w[t] = W2[t];
    __syncthreads();
    int idx = blockIdx.x * 256 + threadIdx.x;
    int row = idx >> 4, j = idx & 15;
    if (row >= N) return;
    const float* zr = z + (size_t)row * H;
    float acc = 0.f;
#pragma unroll
    for (int k = 0; k < H; k++) acc = fmaf(zr[k], w[k * O + j], acc);
    h2p[idx] = acc * dis[row];
}

// ---------- layer 2 aggregation: 1 wave/node, 16 edges in flight ----------
__global__ __launch_bounds__(256) void k_gather2(const float* __restrict__ h2p,
                                                 const float* __restrict__ dis,
                                                 const int* __restrict__ row_ptr,
                                                 const int* __restrict__ col,
                                                 const float* __restrict__ b2,
                                                 float* __restrict__ z2, int N) {
    int node = blockIdx.x * 4 + (threadIdx.x >> 6);
    if (node >= N) return;
    int lane = threadIdx.x & 63;
    int g = lane >> 2;    // edge group 0..15
    int t = lane & 3;     // feature quad
    float4 acc = {0.f, 0.f, 0.f, 0.f};
    int e = row_ptr[node + 1];
#pragma unroll 4
    for (int p = row_ptr[node] + g; p < e; p += 16) {
        int s = col[p];
        float4 v = *(const float4*)(h2p + (size_t)s * O + t * 4);
        acc.x += v.x; acc.y += v.y; acc.z += v.z; acc.w += v.w;
    }
#pragma unroll
    for (int off = 4; off < 64; off <<= 1) {
        acc.x += __shfl_xor(acc.x, off);
        acc.y += __shfl_xor(acc.y, off);
        acc.z += __shfl_xor(acc.z, off);
        acc.w += __shfl_xor(acc.w, off);
    }
    if (g == 0) {
        float dn = dis[node];
        float4 self = *(const float4*)(h2p + (size_t)node * O + t * 4);
        float4 bb = *(const float4*)(b2 + t * 4);
        float4 o;
        o.x = fmaf(acc.x + self.x, dn, bb.x);
        o.y = fmaf(acc.y + self.y, dn, bb.y);
        o.z = fmaf(acc.z + self.z, dn, bb.z);
        o.w = fmaf(acc.w + self.w, dn, bb.w);
        *(float4*)(z2 + (size_t)node * O + t * 4) = o;
    }
}

// ---------- link prediction logits: 4 lanes per pair ----------
__global__ __launch_bounds__(256) void k_logits(const float* __restrict__ z2,
                                                const int* __restrict__ pos,
                                                const int* __restrict__ neg,
                                                float* __restrict__ out, int P, int Q) {
    int tid = blockIdx.x * 256 + threadIdx.x;
    int i = tid >> 2;
    if (i >= P + Q) return;
    int k = tid & 3;
    int a, b;
    if (i < P) { a = pos[i]; b = pos[P + i]; }
    else       { int t = i - P; a = neg[t]; b = neg[Q + t]; }
    float4 va = *(const float4*)(z2 + (size_t)a * O + k * 4);
    float4 vb = *(const float4*)(z2 + (size_t)b * O + k * 4);
    float r = va.x * vb.x + va.y * vb.y + va.z * vb.z + va.w * vb.w;
    r += __shfl_xor(r, 1);
    r += __shfl_xor(r, 2);
    if (k == 0) out[i] = r;
}

extern "C" void kernel_launch(void* const* d_in, const int* in_sizes, int n_in,
                              void* d_out, int out_size, void* d_ws, size_t ws_size,
                              hipStream_t stream) {
    const float* x   = (const float*)d_in[0];
    const int*   ei  = (const int*)d_in[1];
    const int*   pos = (const int*)d_in[2];
    const int*   neg = (const int*)d_in[3];
    const float* W1  = (const float*)d_in[4];
    const float* b1  = (const float*)d_in[5];
    const float* W2  = (const float*)d_in[6];
    const float* b2  = (const float*)d_in[7];
    float* out = (float*)d_out;

    int N = in_sizes[0] / F;
    int E = in_sizes[1] / 2;
    int P = in_sizes[2] / 2;
    int Q = in_sizes[3] / 2;
    const int* src  = ei;
    const int* dstv = ei + E;

    int NB  = (N + 255) / 256;       // scan blocks, <= 1024
    int Npad = NB * 256;
    int Epad = (E + 63) & ~63;

    // workspace layout (all offsets 256B-aligned)
    int*   cnt      = (int*)d_ws;                // N counters (deg after k_rank)
    float* dis      = (float*)(cnt + Npad);
    int*   row_ptr  = (int*)(dis + Npad);        // N+1 entries (Npad+256 reserved)
    int*   partials = row_ptr + Npad + 256;      // 1024 entries
    int*   col      = partials + 1024;           // E entries
    float* h1p      = (float*)(col + Epad);      // N*H floats
    float* z        = h1p + (size_t)N * H;       // N*H
    float* h2p      = z + (size_t)N * H;         // N*O
    float* z2       = h2p + (size_t)N * O;       // N*O
    int*   rank     = (int*)h1p;                 // E ints, aliases h1p (dead until k_gemm1)

    // CSR build: one atomic pass (rank), scan, atomic-free place
    k_zero<<<(Npad + 255) / 256, 256, 0, stream>>>(cnt, Npad);
    k_rank<<<(E + 255) / 256, 256, 0, stream>>>(dstv, cnt, rank, E);
    k_dis<<<(N + 255) / 256, 256, 0, stream>>>(cnt, dis, N);
    k_scan1<<<NB, 256, 0, stream>>>(cnt, row_ptr, partials, N);
    k_scan2<<<1, 1024, 0, stream>>>(partials, NB);
    k_scan3<<<(N + 256) / 256, 256, 0, stream>>>(row_ptr, partials, N, E);
    k_place<<<(E + 255) / 256, 256, 0, stream>>>(src, dstv, rank, row_ptr, col, E);

    // layer 1
    k_gemm1<<<1024, 256, 0, stream>>>(x, W1, dis, h1p, N);
    k_gather1<<<(N + 3) / 4, 256, 0, stream>>>(h1p, dis, row_ptr, col, b1, z, N);

    // layer 2
    k_gemm2<<<(N * O + 255) / 256, 256, 0, stream>>>(z, W2, dis, h2p, N);
    k_gather2<<<(N + 3) / 4, 256, 0, stream>>>(h2p, dis, row_ptr, col, b2, z2, N);

    // logits
    k_logits<<<((P + Q) * 4 + 255) / 256, 256, 0, stream>>>(z2, pos, neg, out, P, Q);
}

// Round 5
// 572.548 us; speedup vs baseline: 2.3184x; 1.0740x over previous
//
#include <hip/hip_runtime.h>

#define F 128
#define H 64
#define O 16

// ---------- CSR build (rank-based, single atomic pass) ----------
__global__ void k_zero(int* __restrict__ p, int n) {
    int i = blockIdx.x * blockDim.x + threadIdx.x;
    if (i < n) p[i] = 0;
}

// fused degree + rank: one atomic per edge, rank written coalesced
__global__ void k_rank(const int* __restrict__ dstv, int* __restrict__ cnt,
                       int* __restrict__ rank, int E) {
    int i = blockIdx.x * blockDim.x + threadIdx.x;
    if (i < E) rank[i] = atomicAdd(&cnt[dstv[i]], 1);
}

__global__ void k_dis(const int* __restrict__ deg, float* __restrict__ dis, int N) {
    int i = blockIdx.x * blockDim.x + threadIdx.x;
    if (i < N) dis[i] = rsqrtf((float)deg[i] + 1.0f);
}

__global__ void k_scan1(const int* __restrict__ deg, int* __restrict__ local,
                        int* __restrict__ partials, int N) {
    __shared__ int s[256];
    int tid = threadIdx.x;
    int i = blockIdx.x * 256 + tid;
    int v = (i < N) ? deg[i] : 0;
    s[tid] = v;
    __syncthreads();
    for (int off = 1; off < 256; off <<= 1) {
        int t = (tid >= off) ? s[tid - off] : 0;
        __syncthreads();
        s[tid] += t;
        __syncthreads();
    }
    if (i < N) local[i] = s[tid] - v;  // exclusive within block
    if (tid == 255) partials[blockIdx.x] = s[255];
}

__global__ void k_scan2(int* __restrict__ partials, int NB) {
    __shared__ int s[1024];
    int tid = threadIdx.x;
    int v = (tid < NB) ? partials[tid] : 0;
    s[tid] = v;
    __syncthreads();
    for (int off = 1; off < 1024; off <<= 1) {
        int t = (tid >= off) ? s[tid - off] : 0;
        __syncthreads();
        s[tid] += t;
        __syncthreads();
    }
    partials[tid] = s[tid] - v;  // exclusive
}

__global__ void k_scan3(int* __restrict__ row_ptr, const int* __restrict__ partials,
                        int N, int E) {
    int i = blockIdx.x * blockDim.x + threadIdx.x;
    if (i < N) {
        row_ptr[i] += partials[i >> 8];
    } else if (i == N) {
        row_ptr[N] = E;
    }
}

// atomic-free placement
__global__ void k_place(const int* __restrict__ src, const int* __restrict__ dstv,
                        const int* __restrict__ rank, const int* __restrict__ row_ptr,
                        int* __restrict__ col, int E) {
    int i = blockIdx.x * blockDim.x + threadIdx.x;
    if (i < E) {
        col[row_ptr[dstv[i]] + rank[i]] = src[i];
    }
}

// ---------- layer 1: h1p = (x @ W1) * dis[row] ----------
// lane = row; W1[k][0..63] is wave-uniform -> SGPRs via s_load; x via LDS chunks.
__global__ __launch_bounds__(64) void k_gemm1(const float* __restrict__ x,
                                              const float* __restrict__ W1,
                                              const float* __restrict__ dis,
                                              float* __restrict__ h1p, int N) {
    __shared__ float xs[64 * 33];  // 64 rows x 32-k chunk, pad 33 (conflict-free reads)
    int lane = threadIdx.x;        // 0..63
    int row0 = blockIdx.x * 64;
    float acc[H];
#pragma unroll
    for (int c = 0; c < H; c++) acc[c] = 0.f;

    for (int kc = 0; kc < 4; kc++) {
        __syncthreads();
        // stage x[row0..row0+63][kc*32 .. +32), coalesced float4, scalar LDS writes
#pragma unroll
        for (int i = 0; i < 8; i++) {
            int r = i * 8 + (lane >> 3);
            int c = (lane & 7) * 4;
            int rr = row0 + r; if (rr >= N) rr = N - 1;
            float4 v = *(const float4*)(x + (size_t)rr * F + kc * 32 + c);
            xs[r * 33 + c + 0] = v.x;
            xs[r * 33 + c + 1] = v.y;
            xs[r * 33 + c + 2] = v.z;
            xs[r * 33 + c + 3] = v.w;
        }
        __syncthreads();
#pragma unroll 1
        for (int k = 0; k < 32; k++) {
            float a = xs[lane * 33 + k];
            const float* wrow = W1 + (size_t)(kc * 32 + k) * H;  // wave-uniform
#pragma unroll
            for (int c = 0; c < H; c++) acc[c] = fmaf(a, wrow[c], acc[c]);
        }
    }
    int row = row0 + lane;
    if (row < N) {
        float d = dis[row];
        float* orow = h1p + (size_t)row * H;
#pragma unroll
        for (int c = 0; c < H; c += 4) {
            float4 o = {acc[c] * d, acc[c + 1] * d, acc[c + 2] * d, acc[c + 3] * d};
            *(float4*)(orow + c) = o;
        }
    }
}

// ---------- layer 1 aggregation: 1 wave/node, 4 edges in flight ----------
__global__ __launch_bounds__(256) void k_gather1(const float* __restrict__ h1p,
                                                 const float* __restrict__ dis,
                                                 const int* __restrict__ row_ptr,
                                                 const int* __restrict__ col,
                                                 const float* __restrict__ b1,
                                                 float* __restrict__ z, int N) {
    int node = blockIdx.x * 4 + (threadIdx.x >> 6);
    if (node >= N) return;
    int lane = threadIdx.x & 63;
    int g = lane >> 4;    // edge group 0..3
    int t = lane & 15;    // feature quad
    float4 acc = {0.f, 0.f, 0.f, 0.f};
    int e = row_ptr[node + 1];
#pragma unroll 8
    for (int p = row_ptr[node] + g; p < e; p += 4) {
        int s = col[p];
        float4 v = *(const float4*)(h1p + (size_t)s * H + t * 4);
        acc.x += v.x; acc.y += v.y; acc.z += v.z; acc.w += v.w;
    }
#pragma unroll
    for (int off = 16; off < 64; off <<= 1) {
        acc.x += __shfl_xor(acc.x, off);
        acc.y += __shfl_xor(acc.y, off);
        acc.z += __shfl_xor(acc.z, off);
        acc.w += __shfl_xor(acc.w, off);
    }
    if (g == 0) {
        float dn = dis[node];
        float4 self = *(const float4*)(h1p + (size_t)node * H + t * 4);
        float4 bb = *(const float4*)(b1 + t * 4);
        float4 o;
        o.x = fmaxf(fmaf(acc.x + self.x, dn, bb.x), 0.f);
        o.y = fmaxf(fmaf(acc.y + self.y, dn, bb.y), 0.f);
        o.z = fmaxf(fmaf(acc.z + self.z, dn, bb.z), 0.f);
        o.w = fmaxf(fmaf(acc.w + self.w, dn, bb.w), 0.f);
        *(float4*)(z + (size_t)node * H + t * 4) = o;
    }
}

// ---------- layer 2: h2p = (z @ W2) * dis[row] ----------
// lane = row; W2[k][0..15] -> SGPRs; z staged in LDS (full K=64).
__global__ __launch_bounds__(64) void k_gemm2(const float* __restrict__ z,
                                              const float* __restrict__ W2,
                                              const float* __restrict__ dis,
                                              float* __restrict__ h2p, int N) {
    __shared__ float zs[64 * 65];  // 64 rows x 64 cols, pad 65
    int lane = threadIdx.x;
    int row0 = blockIdx.x * 64;
    // stage: 16 float4 per lane, coalesced
#pragma unroll
    for (int i = 0; i < 16; i++) {
        int r = i * 4 + (lane >> 4);
        int c = (lane & 15) * 4;
        int rr = row0 + r; if (rr >= N) rr = N - 1;
        float4 v = *(const float4*)(z + (size_t)rr * H + c);
        zs[r * 65 + c + 0] = v.x;
        zs[r * 65 + c + 1] = v.y;
        zs[r * 65 + c + 2] = v.z;
        zs[r * 65 + c + 3] = v.w;
    }
    __syncthreads();
    float acc[O];
#pragma unroll
    for (int c = 0; c < O; c++) acc[c] = 0.f;
#pragma unroll 1
    for (int k = 0; k < H; k++) {
        float a = zs[lane * 65 + k];
        const float* wrow = W2 + (size_t)k * O;  // wave-uniform
#pragma unroll
        for (int c = 0; c < O; c++) acc[c] = fmaf(a, wrow[c], acc[c]);
    }
    int row = row0 + lane;
    if (row < N) {
        float d = dis[row];
        float* orow = h2p + (size_t)row * O;
#pragma unroll
        for (int c = 0; c < O; c += 4) {
            float4 o = {acc[c] * d, acc[c + 1] * d, acc[c + 2] * d, acc[c + 3] * d};
            *(float4*)(orow + c) = o;
        }
    }
}

// ---------- layer 2 aggregation: 1 wave/node, 16 edges in flight ----------
__global__ __launch_bounds__(256) void k_gather2(const float* __restrict__ h2p,
                                                 const float* __restrict__ dis,
                                                 const int* __restrict__ row_ptr,
                                                 const int* __restrict__ col,
                                                 const float* __restrict__ b2,
                                                 float* __restrict__ z2, int N) {
    int node = blockIdx.x * 4 + (threadIdx.x >> 6);
    if (node >= N) return;
    int lane = threadIdx.x & 63;
    int g = lane >> 2;    // edge group 0..15
    int t = lane & 3;     // feature quad
    float4 acc = {0.f, 0.f, 0.f, 0.f};
    int e = row_ptr[node + 1];
#pragma unroll 4
    for (int p = row_ptr[node] + g; p < e; p += 16) {
        int s = col[p];
        float4 v = *(const float4*)(h2p + (size_t)s * O + t * 4);
        acc.x += v.x; acc.y += v.y; acc.z += v.z; acc.w += v.w;
    }
#pragma unroll
    for (int off = 4; off < 64; off <<= 1) {
        acc.x += __shfl_xor(acc.x, off);
        acc.y += __shfl_xor(acc.y, off);
        acc.z += __shfl_xor(acc.z, off);
        acc.w += __shfl_xor(acc.w, off);
    }
    if (g == 0) {
        float dn = dis[node];
        float4 self = *(const float4*)(h2p + (size_t)node * O + t * 4);
        float4 bb = *(const float4*)(b2 + t * 4);
        float4 o;
        o.x = fmaf(acc.x + self.x, dn, bb.x);
        o.y = fmaf(acc.y + self.y, dn, bb.y);
        o.z = fmaf(acc.z + self.z, dn, bb.z);
        o.w = fmaf(acc.w + self.w, dn, bb.w);
        *(float4*)(z2 + (size_t)node * O + t * 4) = o;
    }
}

// ---------- link prediction logits: 4 lanes per pair ----------
__global__ __launch_bounds__(256) void k_logits(const float* __restrict__ z2,
                                                const int* __restrict__ pos,
                                                const int* __restrict__ neg,
                                                float* __restrict__ out, int P, int Q) {
    int tid = blockIdx.x * 256 + threadIdx.x;
    int i = tid >> 2;
    if (i >= P + Q) return;
    int k = tid & 3;
    int a, b;
    if (i < P) { a = pos[i]; b = pos[P + i]; }
    else       { int t = i - P; a = neg[t]; b = neg[Q + t]; }
    float4 va = *(const float4*)(z2 + (size_t)a * O + k * 4);
    float4 vb = *(const float4*)(z2 + (size_t)b * O + k * 4);
    float r = va.x * vb.x + va.y * vb.y + va.z * vb.z + va.w * vb.w;
    r += __shfl_xor(r, 1);
    r += __shfl_xor(r, 2);
    if (k == 0) out[i] = r;
}

extern "C" void kernel_launch(void* const* d_in, const int* in_sizes, int n_in,
                              void* d_out, int out_size, void* d_ws, size_t ws_size,
                              hipStream_t stream) {
    const float* x   = (const float*)d_in[0];
    const int*   ei  = (const int*)d_in[1];
    const int*   pos = (const int*)d_in[2];
    const int*   neg = (const int*)d_in[3];
    const float* W1  = (const float*)d_in[4];
    const float* b1  = (const float*)d_in[5];
    const float* W2  = (const float*)d_in[6];
    const float* b2  = (const float*)d_in[7];
    float* out = (float*)d_out;

    int N = in_sizes[0] / F;
    int E = in_sizes[1] / 2;
    int P = in_sizes[2] / 2;
    int Q = in_sizes[3] / 2;
    const int* src  = ei;
    const int* dstv = ei + E;

    int NB  = (N + 255) / 256;       // scan blocks, <= 1024
    int Npad = NB * 256;
    int Epad = (E + 63) & ~63;

    // workspace layout (all offsets 256B-aligned)
    int*   cnt      = (int*)d_ws;                // N counters (deg after k_rank)
    float* dis      = (float*)(cnt + Npad);
    int*   row_ptr  = (int*)(dis + Npad);        // N+1 entries (Npad+256 reserved)
    int*   partials = row_ptr + Npad + 256;      // 1024 entries
    int*   col      = partials + 1024;           // E entries
    float* h1p      = (float*)(col + Epad);      // N*H floats
    float* z        = h1p + (size_t)N * H;       // N*H
    float* h2p      = z + (size_t)N * H;         // N*O
    float* z2       = h2p + (size_t)N * O;       // N*O
    int*   rank     = (int*)h1p;                 // E ints, aliases h1p (dead until k_gemm1)

    // CSR build: one atomic pass (rank), scan, atomic-free place
    k_zero<<<(Npad + 255) / 256, 256, 0, stream>>>(cnt, Npad);
    k_rank<<<(E + 255) / 256, 256, 0, stream>>>(dstv, cnt, rank, E);
    k_dis<<<(N + 255) / 256, 256, 0, stream>>>(cnt, dis, N);
    k_scan1<<<NB, 256, 0, stream>>>(cnt, row_ptr, partials, N);
    k_scan2<<<1, 1024, 0, stream>>>(partials, NB);
    k_scan3<<<(N + 256) / 256, 256, 0, stream>>>(row_ptr, partials, N, E);
    k_place<<<(E + 255) / 256, 256, 0, stream>>>(src, dstv, rank, row_ptr, col, E);

    // layer 1
    k_gemm1<<<(N + 63) / 64, 64, 0, stream>>>(x, W1, dis, h1p, N);
    k_gather1<<<(N + 3) / 4, 256, 0, stream>>>(h1p, dis, row_ptr, col, b1, z, N);

    // layer 2
    k_gemm2<<<(N + 63) / 64, 64, 0, stream>>>(z, W2, dis, h2p, N);
    k_gather2<<<(N + 3) / 4, 256, 0, stream>>>(h2p, dis, row_ptr, col, b2, z2, N);

    // logits
    k_logits<<<((P + Q) * 4 + 255) / 256, 256, 0, stream>>>(z2, pos, neg, out, P, Q);
}

// Round 6
// 478.517 us; speedup vs baseline: 2.7740x; 1.1965x over previous
//
#include <hip/hip_runtime.h>

#define F 128
#define H 64
#define O 16

#define BSHIFT 7
#define BSZ 128       // nodes per coarse bucket
#define BCAP 5120     // edge capacity per bucket region (avg 4096, 16-sigma margin)
#define ACHUNK 8192   // edges per bucketA block

// ---------- CSR build: LDS-aggregated multisplit ----------
__global__ void k_bcur2(int* __restrict__ bcur, int NBK) {
    int i = blockIdx.x * blockDim.x + threadIdx.x;
    if (i < NBK) bcur[i] = i * BCAP;
}

// Phase A: coarse bucket scatter with per-block LDS histogram + range reservation.
// Global atomics: one per (block, nonempty bucket) ~ 306K instead of 3.2M.
__global__ __launch_bounds__(256) void k_bucketA(const int* __restrict__ src,
                                                 const int* __restrict__ dstv,
                                                 int* __restrict__ bcur,
                                                 int* __restrict__ bdata, int E) {
    __shared__ int hist[1024];
    for (int t = threadIdx.x; t < 1024; t += 256) hist[t] = 0;
    __syncthreads();
    int base = blockIdx.x * ACHUNK;
    int end = min(base + ACHUNK, E);
    // pass 1: count buckets
    for (int i = base + threadIdx.x; i < end; i += 256) {
        atomicAdd(&hist[dstv[i] >> BSHIFT], 1);
    }
    __syncthreads();
    // reserve contiguous global ranges; hist[b] becomes the running global cursor
    for (int b = threadIdx.x; b < 1024; b += 256) {
        int c = hist[b];
        if (c > 0) hist[b] = atomicAdd(&bcur[b], c);
    }
    __syncthreads();
    // pass 2: place packed (src<<7 | local_dst) via LDS cursors
    for (int i = base + threadIdx.x; i < end; i += 256) {
        int d = dstv[i];
        int b = d >> BSHIFT;
        int pos = atomicAdd(&hist[b], 1);
        bdata[pos] = (src[i] << BSHIFT) | (d & (BSZ - 1));
    }
}

// Phase B1: per-bucket degree histogram in LDS, coalesced deg write, no global atomics
__global__ __launch_bounds__(256) void k_bdeg(const int* __restrict__ bdata,
                                              const int* __restrict__ bcur,
                                              int* __restrict__ deg, int N) {
    __shared__ int h[BSZ];
    int b = blockIdx.x;
    int node0 = b << BSHIFT;
    int nloc = min(BSZ, N - node0);
    for (int t = threadIdx.x; t < BSZ; t += 256) h[t] = 0;
    __syncthreads();
    int start = b * BCAP;
    int end = bcur[b];  // = start + bucket count after phase A
    for (int p = start + threadIdx.x; p < end; p += 256)
        atomicAdd(&h[bdata[p] & (BSZ - 1)], 1);
    __syncthreads();
    for (int t = threadIdx.x; t < nloc; t += 256) deg[node0 + t] = h[t];
}

__global__ void k_dis(const int* __restrict__ deg, float* __restrict__ dis, int N) {
    int i = blockIdx.x * blockDim.x + threadIdx.x;
    if (i < N) dis[i] = rsqrtf((float)deg[i] + 1.0f);
}

__global__ void k_scan1(const int* __restrict__ deg, int* __restrict__ local,
                        int* __restrict__ partials, int N) {
    __shared__ int s[256];
    int tid = threadIdx.x;
    int i = blockIdx.x * 256 + tid;
    int v = (i < N) ? deg[i] : 0;
    s[tid] = v;
    __syncthreads();
    for (int off = 1; off < 256; off <<= 1) {
        int t = (tid >= off) ? s[tid - off] : 0;
        __syncthreads();
        s[tid] += t;
        __syncthreads();
    }
    if (i < N) local[i] = s[tid] - v;  // exclusive within block
    if (tid == 255) partials[blockIdx.x] = s[255];
}

__global__ void k_scan2(int* __restrict__ partials, int NB) {
    __shared__ int s[1024];
    int tid = threadIdx.x;
    int v = (tid < NB) ? partials[tid] : 0;
    s[tid] = v;
    __syncthreads();
    for (int off = 1; off < 1024; off <<= 1) {
        int t = (tid >= off) ? s[tid - off] : 0;
        __syncthreads();
        s[tid] += t;
        __syncthreads();
    }
    partials[tid] = s[tid] - v;  // exclusive
}

__global__ void k_scan3(int* __restrict__ row_ptr, const int* __restrict__ partials,
                        int N, int E) {
    int i = blockIdx.x * blockDim.x + threadIdx.x;
    if (i < N) {
        row_ptr[i] += partials[i >> 8];
    } else if (i == N) {
        row_ptr[N] = E;
    }
}

// Phase B2: per-bucket exact CSR placement; stores confined to ~16KB L2-hot window
__global__ __launch_bounds__(256) void k_bplace(const int* __restrict__ bdata,
                                                const int* __restrict__ bcur,
                                                const int* __restrict__ row_ptr,
                                                int* __restrict__ col, int N) {
    __shared__ int cur[BSZ];
    int b = blockIdx.x;
    int node0 = b << BSHIFT;
    int nloc = min(BSZ, N - node0);
    for (int t = threadIdx.x; t < nloc; t += 256) cur[t] = row_ptr[node0 + t];
    __syncthreads();
    int start = b * BCAP;
    int end = bcur[b];
    for (int p = start + threadIdx.x; p < end; p += 256) {
        int v = bdata[p];
        int pos = atomicAdd(&cur[v & (BSZ - 1)], 1);
        col[pos] = v >> BSHIFT;
    }
}

// ---------- layer 1: h1p = (x @ W1) * dis[row] ----------
// lane = row; W1[k][0..63] is wave-uniform -> SGPRs; x via LDS chunks.
__global__ __launch_bounds__(64) void k_gemm1(const float* __restrict__ x,
                                              const float* __restrict__ W1,
                                              const float* __restrict__ dis,
                                              float* __restrict__ h1p, int N) {
    __shared__ float xs[64 * 33];
    int lane = threadIdx.x;
    int row0 = blockIdx.x * 64;
    float acc[H];
#pragma unroll
    for (int c = 0; c < H; c++) acc[c] = 0.f;

    for (int kc = 0; kc < 4; kc++) {
        __syncthreads();
#pragma unroll
        for (int i = 0; i < 8; i++) {
            int r = i * 8 + (lane >> 3);
            int c = (lane & 7) * 4;
            int rr = row0 + r; if (rr >= N) rr = N - 1;
            float4 v = *(const float4*)(x + (size_t)rr * F + kc * 32 + c);
            xs[r * 33 + c + 0] = v.x;
            xs[r * 33 + c + 1] = v.y;
            xs[r * 33 + c + 2] = v.z;
            xs[r * 33 + c + 3] = v.w;
        }
        __syncthreads();
#pragma unroll 1
        for (int k = 0; k < 32; k++) {
            float a = xs[lane * 33 + k];
            const float* wrow = W1 + (size_t)(kc * 32 + k) * H;  // wave-uniform
#pragma unroll
            for (int c = 0; c < H; c++) acc[c] = fmaf(a, wrow[c], acc[c]);
        }
    }
    int row = row0 + lane;
    if (row < N) {
        float d = dis[row];
        float* orow = h1p + (size_t)row * H;
#pragma unroll
        for (int c = 0; c < H; c += 4) {
            float4 o = {acc[c] * d, acc[c + 1] * d, acc[c + 2] * d, acc[c + 3] * d};
            *(float4*)(orow + c) = o;
        }
    }
}

// ---------- layer 1 aggregation: 1 wave/node, 4 edges in flight ----------
__global__ __launch_bounds__(256) void k_gather1(const float* __restrict__ h1p,
                                                 const float* __restrict__ dis,
                                                 const int* __restrict__ row_ptr,
                                                 const int* __restrict__ col,
                                                 const float* __restrict__ b1,
                                                 float* __restrict__ z, int N) {
    int node = blockIdx.x * 4 + (threadIdx.x >> 6);
    if (node >= N) return;
    int lane = threadIdx.x & 63;
    int g = lane >> 4;
    int t = lane & 15;
    float4 acc = {0.f, 0.f, 0.f, 0.f};
    int e = row_ptr[node + 1];
#pragma unroll 8
    for (int p = row_ptr[node] + g; p < e; p += 4) {
        int s = col[p];
        float4 v = *(const float4*)(h1p + (size_t)s * H + t * 4);
        acc.x += v.x; acc.y += v.y; acc.z += v.z; acc.w += v.w;
    }
#pragma unroll
    for (int off = 16; off < 64; off <<= 1) {
        acc.x += __shfl_xor(acc.x, off);
        acc.y += __shfl_xor(acc.y, off);
        acc.z += __shfl_xor(acc.z, off);
        acc.w += __shfl_xor(acc.w, off);
    }
    if (g == 0) {
        float dn = dis[node];
        float4 self = *(const float4*)(h1p + (size_t)node * H + t * 4);
        float4 bb = *(const float4*)(b1 + t * 4);
        float4 o;
        o.x = fmaxf(fmaf(acc.x + self.x, dn, bb.x), 0.f);
        o.y = fmaxf(fmaf(acc.y + self.y, dn, bb.y), 0.f);
        o.z = fmaxf(fmaf(acc.z + self.z, dn, bb.z), 0.f);
        o.w = fmaxf(fmaf(acc.w + self.w, dn, bb.w), 0.f);
        *(float4*)(z + (size_t)node * H + t * 4) = o;
    }
}

// ---------- layer 2: h2p = (z @ W2) * dis[row] ----------
__global__ __launch_bounds__(64) void k_gemm2(const float* __restrict__ z,
                                              const float* __restrict__ W2,
                                              const float* __restrict__ dis,
                                              float* __restrict__ h2p, int N) {
    __shared__ float zs[64 * 65];
    int lane = threadIdx.x;
    int row0 = blockIdx.x * 64;
#pragma unroll
    for (int i = 0; i < 16; i++) {
        int r = i * 4 + (lane >> 4);
        int c = (lane & 15) * 4;
        int rr = row0 + r; if (rr >= N) rr = N - 1;
        float4 v = *(const float4*)(z + (size_t)rr * H + c);
        zs[r * 65 + c + 0] = v.x;
        zs[r * 65 + c + 1] = v.y;
        zs[r * 65 + c + 2] = v.z;
        zs[r * 65 + c + 3] = v.w;
    }
    __syncthreads();
    float acc[O];
#pragma unroll
    for (int c = 0; c < O; c++) acc[c] = 0.f;
#pragma unroll 1
    for (int k = 0; k < H; k++) {
        float a = zs[lane * 65 + k];
        const float* wrow = W2 + (size_t)k * O;  // wave-uniform
#pragma unroll
        for (int c = 0; c < O; c++) acc[c] = fmaf(a, wrow[c], acc[c]);
    }
    int row = row0 + lane;
    if (row < N) {
        float d = dis[row];
        float* orow = h2p + (size_t)row * O;
#pragma unroll
        for (int c = 0; c < O; c += 4) {
            float4 o = {acc[c] * d, acc[c + 1] * d, acc[c + 2] * d, acc[c + 3] * d};
            *(float4*)(orow + c) = o;
        }
    }
}

// ---------- layer 2 aggregation: 1 wave/node, 16 edges in flight ----------
__global__ __launch_bounds__(256) void k_gather2(const float* __restrict__ h2p,
                                                 const float* __restrict__ dis,
                                                 const int* __restrict__ row_ptr,
                                                 const int* __restrict__ col,
                                                 const float* __restrict__ b2,
                                                 float* __restrict__ z2, int N) {
    int node = blockIdx.x * 4 + (threadIdx.x >> 6);
    if (node >= N) return;
    int lane = threadIdx.x & 63;
    int g = lane >> 2;
    int t = lane & 3;
    float4 acc = {0.f, 0.f, 0.f, 0.f};
    int e = row_ptr[node + 1];
#pragma unroll 4
    for (int p = row_ptr[node] + g; p < e; p += 16) {
        int s = col[p];
        float4 v = *(const float4*)(h2p + (size_t)s * O + t * 4);
        acc.x += v.x; acc.y += v.y; acc.z += v.z; acc.w += v.w;
    }
#pragma unroll
    for (int off = 4; off < 64; off <<= 1) {
        acc.x += __shfl_xor(acc.x, off);
        acc.y += __shfl_xor(acc.y, off);
        acc.z += __shfl_xor(acc.z, off);
        acc.w += __shfl_xor(acc.w, off);
    }
    if (g == 0) {
        float dn = dis[node];
        float4 self = *(const float4*)(h2p + (size_t)node * O + t * 4);
        float4 bb = *(const float4*)(b2 + t * 4);
        float4 o;
        o.x = fmaf(acc.x + self.x, dn, bb.x);
        o.y = fmaf(acc.y + self.y, dn, bb.y);
        o.z = fmaf(acc.z + self.z, dn, bb.z);
        o.w = fmaf(acc.w + self.w, dn, bb.w);
        *(float4*)(z2 + (size_t)node * O + t * 4) = o;
    }
}

// ---------- link prediction logits: 4 lanes per pair ----------
__global__ __launch_bounds__(256) void k_logits(const float* __restrict__ z2,
                                                const int* __restrict__ pos,
                                                const int* __restrict__ neg,
                                                float* __restrict__ out, int P, int Q) {
    int tid = blockIdx.x * 256 + threadIdx.x;
    int i = tid >> 2;
    if (i >= P + Q) return;
    int k = tid & 3;
    int a, b;
    if (i < P) { a = pos[i]; b = pos[P + i]; }
    else       { int t = i - P; a = neg[t]; b = neg[Q + t]; }
    float4 va = *(const float4*)(z2 + (size_t)a * O + k * 4);
    float4 vb = *(const float4*)(z2 + (size_t)b * O + k * 4);
    float r = va.x * vb.x + va.y * vb.y + va.z * vb.z + va.w * vb.w;
    r += __shfl_xor(r, 1);
    r += __shfl_xor(r, 2);
    if (k == 0) out[i] = r;
}

extern "C" void kernel_launch(void* const* d_in, const int* in_sizes, int n_in,
                              void* d_out, int out_size, void* d_ws, size_t ws_size,
                              hipStream_t stream) {
    const float* x   = (const float*)d_in[0];
    const int*   ei  = (const int*)d_in[1];
    const int*   pos = (const int*)d_in[2];
    const int*   neg = (const int*)d_in[3];
    const float* W1  = (const float*)d_in[4];
    const float* b1  = (const float*)d_in[5];
    const float* W2  = (const float*)d_in[6];
    const float* b2  = (const float*)d_in[7];
    float* out = (float*)d_out;

    int N = in_sizes[0] / F;
    int E = in_sizes[1] / 2;
    int P = in_sizes[2] / 2;
    int Q = in_sizes[3] / 2;
    const int* src  = ei;
    const int* dstv = ei + E;

    int NB  = (N + 255) / 256;        // scan blocks, <= 1024
    int Npad = NB * 256;
    int Epad = (E + 63) & ~63;
    int NBK = (N + BSZ - 1) / BSZ;    // coarse buckets (782)

    // workspace layout (all offsets 256B-aligned)
    int*   deg      = (int*)d_ws;                // N counters
    float* dis      = (float*)(deg + Npad);
    int*   row_ptr  = (int*)(dis + Npad);        // N+1 entries (Npad+256 reserved)
    int*   bcur     = row_ptr + Npad + 256;      // NBK cursors (pad to 1024)
    int*   partials = bcur + 1024;               // 1024 entries
    int*   col      = partials + 1024;           // E entries
    float* h1p      = (float*)(col + Epad);      // N*H floats
    float* z        = h1p + (size_t)N * H;       // N*H
    float* h2p      = z + (size_t)N * H;         // N*O
    float* z2       = h2p + (size_t)N * O;       // N*O
    int*   bdata    = (int*)h1p;                 // NBK*BCAP ints (16MB), aliases h1p
                                                 // (dead until k_gemm1 writes it)

    // CSR build: multisplit reservation
    k_bcur2<<<(NBK + 255) / 256, 256, 0, stream>>>(bcur, NBK);
    k_bucketA<<<(E + ACHUNK - 1) / ACHUNK, 256, 0, stream>>>(src, dstv, bcur, bdata, E);
    k_bdeg<<<NBK, 256, 0, stream>>>(bdata, bcur, deg, N);
    k_dis<<<(N + 255) / 256, 256, 0, stream>>>(deg, dis, N);
    k_scan1<<<NB, 256, 0, stream>>>(deg, row_ptr, partials, N);
    k_scan2<<<1, 1024, 0, stream>>>(partials, NB);
    k_scan3<<<(N + 256) / 256, 256, 0, stream>>>(row_ptr, partials, N, E);
    k_bplace<<<NBK, 256, 0, stream>>>(bdata, bcur, row_ptr, col, N);

    // layer 1
    k_gemm1<<<(N + 63) / 64, 64, 0, stream>>>(x, W1, dis, h1p, N);
    k_gather1<<<(N + 3) / 4, 256, 0, stream>>>(h1p, dis, row_ptr, col, b1, z, N);

    // layer 2
    k_gemm2<<<(N + 63) / 64, 64, 0, stream>>>(z, W2, dis, h2p, N);
    k_gather2<<<(N + 3) / 4, 256, 0, stream>>>(h2p, dis, row_ptr, col, b2, z2, N);

    // logits
    k_logits<<<((P + Q) * 4 + 255) / 256, 256, 0, stream>>>(z2, pos, neg, out, P, Q);
}

// Round 7
// 425.555 us; speedup vs baseline: 3.1192x; 1.1245x over previous
//
#include <hip/hip_runtime.h>

#define F 128
#define H 64
#define O 16

#define BSHIFT 7
#define BSZ 128       // nodes per coarse bucket
#define BCAP 5120     // edge capacity per bucket region (avg 4096, 16-sigma margin)
#define ACHUNK 8192   // edges per bucketA block

typedef _Float16 half8_t __attribute__((ext_vector_type(8)));

// ---------- CSR build: LDS-aggregated multisplit ----------
__global__ void k_bcur2(int* __restrict__ bcur, int NBK) {
    int i = blockIdx.x * blockDim.x + threadIdx.x;
    if (i < NBK) bcur[i] = i * BCAP;
}

__global__ __launch_bounds__(256) void k_bucketA(const int* __restrict__ src,
                                                 const int* __restrict__ dstv,
                                                 int* __restrict__ bcur,
                                                 int* __restrict__ bdata, int E) {
    __shared__ int hist[1024];
    for (int t = threadIdx.x; t < 1024; t += 256) hist[t] = 0;
    __syncthreads();
    int base = blockIdx.x * ACHUNK;
    int end = min(base + ACHUNK, E);
    for (int i = base + threadIdx.x; i < end; i += 256) {
        atomicAdd(&hist[dstv[i] >> BSHIFT], 1);
    }
    __syncthreads();
    for (int b = threadIdx.x; b < 1024; b += 256) {
        int c = hist[b];
        if (c > 0) hist[b] = atomicAdd(&bcur[b], c);
    }
    __syncthreads();
    for (int i = base + threadIdx.x; i < end; i += 256) {
        int d = dstv[i];
        int b = d >> BSHIFT;
        int pos = atomicAdd(&hist[b], 1);
        bdata[pos] = (src[i] << BSHIFT) | (d & (BSZ - 1));
    }
}

__global__ __launch_bounds__(256) void k_bdeg(const int* __restrict__ bdata,
                                              const int* __restrict__ bcur,
                                              int* __restrict__ deg, int N) {
    __shared__ int h[BSZ];
    int b = blockIdx.x;
    int node0 = b << BSHIFT;
    int nloc = min(BSZ, N - node0);
    for (int t = threadIdx.x; t < BSZ; t += 256) h[t] = 0;
    __syncthreads();
    int start = b * BCAP;
    int end = bcur[b];
    for (int p = start + threadIdx.x; p < end; p += 256)
        atomicAdd(&h[bdata[p] & (BSZ - 1)], 1);
    __syncthreads();
    for (int t = threadIdx.x; t < nloc; t += 256) deg[node0 + t] = h[t];
}

__global__ void k_dis(const int* __restrict__ deg, float* __restrict__ dis, int N) {
    int i = blockIdx.x * blockDim.x + threadIdx.x;
    if (i < N) dis[i] = rsqrtf((float)deg[i] + 1.0f);
}

__global__ void k_scan1(const int* __restrict__ deg, int* __restrict__ local,
                        int* __restrict__ partials, int N) {
    __shared__ int s[256];
    int tid = threadIdx.x;
    int i = blockIdx.x * 256 + tid;
    int v = (i < N) ? deg[i] : 0;
    s[tid] = v;
    __syncthreads();
    for (int off = 1; off < 256; off <<= 1) {
        int t = (tid >= off) ? s[tid - off] : 0;
        __syncthreads();
        s[tid] += t;
        __syncthreads();
    }
    if (i < N) local[i] = s[tid] - v;
    if (tid == 255) partials[blockIdx.x] = s[255];
}

__global__ void k_scan2(int* __restrict__ partials, int NB) {
    __shared__ int s[1024];
    int tid = threadIdx.x;
    int v = (tid < NB) ? partials[tid] : 0;
    s[tid] = v;
    __syncthreads();
    for (int off = 1; off < 1024; off <<= 1) {
        int t = (tid >= off) ? s[tid - off] : 0;
        __syncthreads();
        s[tid] += t;
        __syncthreads();
    }
    partials[tid] = s[tid] - v;
}

__global__ void k_scan3(int* __restrict__ row_ptr, const int* __restrict__ partials,
                        int N, int E) {
    int i = blockIdx.x * blockDim.x + threadIdx.x;
    if (i < N) {
        row_ptr[i] += partials[i >> 8];
    } else if (i == N) {
        row_ptr[N] = E;
    }
}

__global__ __launch_bounds__(256) void k_bplace(const int* __restrict__ bdata,
                                                const int* __restrict__ bcur,
                                                const int* __restrict__ row_ptr,
                                                int* __restrict__ col, int N) {
    __shared__ int cur[BSZ];
    int b = blockIdx.x;
    int node0 = b << BSHIFT;
    int nloc = min(BSZ, N - node0);
    for (int t = threadIdx.x; t < nloc; t += 256) cur[t] = row_ptr[node0 + t];
    __syncthreads();
    int start = b * BCAP;
    int end = bcur[b];
    for (int p = start + threadIdx.x; p < end; p += 256) {
        int v = bdata[p];
        int pos = atomicAdd(&cur[v & (BSZ - 1)], 1);
        col[pos] = v >> BSHIFT;
    }
}

// ---------- layer 1: h1p = fp16( (x @ W1) * dis[row] ) ----------
__global__ __launch_bounds__(64) void k_gemm1(const float* __restrict__ x,
                                              const float* __restrict__ W1,
                                              const float* __restrict__ dis,
                                              _Float16* __restrict__ h1p, int N) {
    __shared__ float xs[64 * 33];
    int lane = threadIdx.x;
    int row0 = blockIdx.x * 64;
    float acc[H];
#pragma unroll
    for (int c = 0; c < H; c++) acc[c] = 0.f;

    for (int kc = 0; kc < 4; kc++) {
        __syncthreads();
#pragma unroll
        for (int i = 0; i < 8; i++) {
            int r = i * 8 + (lane >> 3);
            int c = (lane & 7) * 4;
            int rr = row0 + r; if (rr >= N) rr = N - 1;
            float4 v = *(const float4*)(x + (size_t)rr * F + kc * 32 + c);
            xs[r * 33 + c + 0] = v.x;
            xs[r * 33 + c + 1] = v.y;
            xs[r * 33 + c + 2] = v.z;
            xs[r * 33 + c + 3] = v.w;
        }
        __syncthreads();
#pragma unroll 1
        for (int k = 0; k < 32; k++) {
            float a = xs[lane * 33 + k];
            const float* wrow = W1 + (size_t)(kc * 32 + k) * H;  // wave-uniform -> SGPRs
#pragma unroll
            for (int c = 0; c < H; c++) acc[c] = fmaf(a, wrow[c], acc[c]);
        }
    }
    int row = row0 + lane;
    if (row < N) {
        float d = dis[row];
        half8_t* orow = (half8_t*)(h1p + (size_t)row * H);
#pragma unroll
        for (int c0 = 0; c0 < H; c0 += 8) {
            half8_t o;
#pragma unroll
            for (int j = 0; j < 8; j++) o[j] = (_Float16)(acc[c0 + j] * d);
            orow[c0 / 8] = o;
        }
    }
}

// ---------- layer 1 aggregation: 1 wave/node, 8 edges in flight, fp16 rows ----------
__global__ __launch_bounds__(256) void k_gather1(const _Float16* __restrict__ h1p,
                                                 const float* __restrict__ dis,
                                                 const int* __restrict__ row_ptr,
                                                 const int* __restrict__ col,
                                                 const float* __restrict__ b1,
                                                 float* __restrict__ z, int N) {
    int node = blockIdx.x * 4 + (threadIdx.x >> 6);
    if (node >= N) return;
    int lane = threadIdx.x & 63;
    int g = lane >> 3;   // edge group 0..7
    int t = lane & 7;    // 8-feature slot
    const half8_t* hp = (const half8_t*)h1p;
    float acc[8];
#pragma unroll
    for (int j = 0; j < 8; j++) acc[j] = 0.f;
    int e = row_ptr[node + 1];
    for (int p = row_ptr[node] + g; p < e; p += 8) {
        int s = col[p];
        half8_t v = hp[(size_t)s * 8 + t];
#pragma unroll
        for (int j = 0; j < 8; j++) acc[j] += (float)v[j];
    }
#pragma unroll
    for (int off = 8; off < 64; off <<= 1) {
#pragma unroll
        for (int j = 0; j < 8; j++) acc[j] += __shfl_xor(acc[j], off);
    }
    if (g == 0) {
        float dn = dis[node];
        half8_t self = hp[(size_t)node * 8 + t];
        float o[8];
#pragma unroll
        for (int j = 0; j < 8; j++)
            o[j] = fmaxf(fmaf(acc[j] + (float)self[j], dn, b1[t * 8 + j]), 0.f);
        float4* zp = (float4*)(z + (size_t)node * H + t * 8);
        zp[0] = float4{o[0], o[1], o[2], o[3]};
        zp[1] = float4{o[4], o[5], o[6], o[7]};
    }
}

// ---------- layer 2: h2p = fp16( (z @ W2) * dis[row] ) ----------
__global__ __launch_bounds__(64) void k_gemm2(const float* __restrict__ z,
                                              const float* __restrict__ W2,
                                              const float* __restrict__ dis,
                                              _Float16* __restrict__ h2p, int N) {
    __shared__ float zs[64 * 65];
    int lane = threadIdx.x;
    int row0 = blockIdx.x * 64;
#pragma unroll
    for (int i = 0; i < 16; i++) {
        int r = i * 4 + (lane >> 4);
        int c = (lane & 15) * 4;
        int rr = row0 + r; if (rr >= N) rr = N - 1;
        float4 v = *(const float4*)(z + (size_t)rr * H + c);
        zs[r * 65 + c + 0] = v.x;
        zs[r * 65 + c + 1] = v.y;
        zs[r * 65 + c + 2] = v.z;
        zs[r * 65 + c + 3] = v.w;
    }
    __syncthreads();
    float acc[O];
#pragma unroll
    for (int c = 0; c < O; c++) acc[c] = 0.f;
#pragma unroll 1
    for (int k = 0; k < H; k++) {
        float a = zs[lane * 65 + k];
        const float* wrow = W2 + (size_t)k * O;  // wave-uniform
#pragma unroll
        for (int c = 0; c < O; c++) acc[c] = fmaf(a, wrow[c], acc[c]);
    }
    int row = row0 + lane;
    if (row < N) {
        float d = dis[row];
        half8_t* orow = (half8_t*)(h2p + (size_t)row * O);
#pragma unroll
        for (int c0 = 0; c0 < O; c0 += 8) {
            half8_t o;
#pragma unroll
            for (int j = 0; j < 8; j++) o[j] = (_Float16)(acc[c0 + j] * d);
            orow[c0 / 8] = o;
        }
    }
}

// ---------- layer 2 aggregation: 1 wave/node, 32 edges in flight, fp16 rows ----------
__global__ __launch_bounds__(256) void k_gather2(const _Float16* __restrict__ h2p,
                                                 const float* __restrict__ dis,
                                                 const int* __restrict__ row_ptr,
                                                 const int* __restrict__ col,
                                                 const float* __restrict__ b2,
                                                 float* __restrict__ z2, int N) {
    int node = blockIdx.x * 4 + (threadIdx.x >> 6);
    if (node >= N) return;
    int lane = threadIdx.x & 63;
    int g = lane >> 1;   // edge group 0..31
    int t = lane & 1;    // 8-feature slot (2 x 8 = 16)
    const half8_t* hp = (const half8_t*)h2p;
    float acc[8];
#pragma unroll
    for (int j = 0; j < 8; j++) acc[j] = 0.f;
    int e = row_ptr[node + 1];
    for (int p = row_ptr[node] + g; p < e; p += 32) {
        int s = col[p];
        half8_t v = hp[(size_t)s * 2 + t];
#pragma unroll
        for (int j = 0; j < 8; j++) acc[j] += (float)v[j];
    }
#pragma unroll
    for (int off = 2; off < 64; off <<= 1) {
#pragma unroll
        for (int j = 0; j < 8; j++) acc[j] += __shfl_xor(acc[j], off);
    }
    if (g == 0) {
        float dn = dis[node];
        half8_t self = hp[(size_t)node * 2 + t];
        float o[8];
#pragma unroll
        for (int j = 0; j < 8; j++)
            o[j] = fmaf(acc[j] + (float)self[j], dn, b2[t * 8 + j]);
        float4* zp = (float4*)(z2 + (size_t)node * O + t * 8);
        zp[0] = float4{o[0], o[1], o[2], o[3]};
        zp[1] = float4{o[4], o[5], o[6], o[7]};
    }
}

// ---------- link prediction logits: 4 lanes per pair ----------
__global__ __launch_bounds__(256) void k_logits(const float* __restrict__ z2,
                                                const int* __restrict__ pos,
                                                const int* __restrict__ neg,
                                                float* __restrict__ out, int P, int Q) {
    int tid = blockIdx.x * 256 + threadIdx.x;
    int i = tid >> 2;
    if (i >= P + Q) return;
    int k = tid & 3;
    int a, b;
    if (i < P) { a = pos[i]; b = pos[P + i]; }
    else       { int t = i - P; a = neg[t]; b = neg[Q + t]; }
    float4 va = *(const float4*)(z2 + (size_t)a * O + k * 4);
    float4 vb = *(const float4*)(z2 + (size_t)b * O + k * 4);
    float r = va.x * vb.x + va.y * vb.y + va.z * vb.z + va.w * vb.w;
    r += __shfl_xor(r, 1);
    r += __shfl_xor(r, 2);
    if (k == 0) out[i] = r;
}

extern "C" void kernel_launch(void* const* d_in, const int* in_sizes, int n_in,
                              void* d_out, int out_size, void* d_ws, size_t ws_size,
                              hipStream_t stream) {
    const float* x   = (const float*)d_in[0];
    const int*   ei  = (const int*)d_in[1];
    const int*   pos = (const int*)d_in[2];
    const int*   neg = (const int*)d_in[3];
    const float* W1  = (const float*)d_in[4];
    const float* b1  = (const float*)d_in[5];
    const float* W2  = (const float*)d_in[6];
    const float* b2  = (const float*)d_in[7];
    float* out = (float*)d_out;

    int N = in_sizes[0] / F;
    int E = in_sizes[1] / 2;
    int P = in_sizes[2] / 2;
    int Q = in_sizes[3] / 2;
    const int* src  = ei;
    const int* dstv = ei + E;

    int NB  = (N + 255) / 256;        // scan blocks, <= 1024
    int Npad = NB * 256;
    int Epad = (E + 63) & ~63;
    int NBK = (N + BSZ - 1) / BSZ;    // coarse buckets

    // workspace layout (byte-exact; all region sizes multiples of 256B)
    char* w = (char*)d_ws;
    int*   deg      = (int*)w;        w += (size_t)Npad * 4;
    float* dis      = (float*)w;      w += (size_t)Npad * 4;
    int*   row_ptr  = (int*)w;        w += (size_t)(Npad + 256) * 4;
    int*   bcur     = (int*)w;        w += 1024 * 4;
    int*   partials = (int*)w;        w += 1024 * 4;
    int*   col      = (int*)w;        w += (size_t)Epad * 4;
    // h1p (fp16, N*H*2 = 12.8MB) aliases bdata (NBK*BCAP*4 = 16MB); reserve max.
    _Float16* h1p   = (_Float16*)w;
    int*      bdata = (int*)w;
    size_t h1b = (size_t)N * H * 2, bdb = (size_t)NBK * BCAP * 4;
    w += (h1b > bdb ? h1b : bdb);
    float*    z     = (float*)w;      w += (size_t)N * H * 4;
    _Float16* h2p   = (_Float16*)w;   w += (size_t)N * O * 2;
    float*    z2    = (float*)w;

    // CSR build: multisplit reservation
    k_bcur2<<<(NBK + 255) / 256, 256, 0, stream>>>(bcur, NBK);
    k_bucketA<<<(E + ACHUNK - 1) / ACHUNK, 256, 0, stream>>>(src, dstv, bcur, bdata, E);
    k_bdeg<<<NBK, 256, 0, stream>>>(bdata, bcur, deg, N);
    k_dis<<<(N + 255) / 256, 256, 0, stream>>>(deg, dis, N);
    k_scan1<<<NB, 256, 0, stream>>>(deg, row_ptr, partials, N);
    k_scan2<<<1, 1024, 0, stream>>>(partials, NB);
    k_scan3<<<(N + 256) / 256, 256, 0, stream>>>(row_ptr, partials, N, E);
    k_bplace<<<NBK, 256, 0, stream>>>(bdata, bcur, row_ptr, col, N);

    // layer 1
    k_gemm1<<<(N + 63) / 64, 64, 0, stream>>>(x, W1, dis, h1p, N);
    k_gather1<<<(N + 3) / 4, 256, 0, stream>>>(h1p, dis, row_ptr, col, b1, z, N);

    // layer 2
    k_gemm2<<<(N + 63) / 64, 64, 0, stream>>>(z, W2, dis, h2p, N);
    k_gather2<<<(N + 3) / 4, 256, 0, stream>>>(h2p, dis, row_ptr, col, b2, z2, N);

    // logits
    k_logits<<<((P + Q) * 4 + 255) / 256, 256, 0, stream>>>(z2, pos, neg, out, P, Q);
}